// Round 5
// baseline (190.714 us; speedup 1.0000x reference)
//
#include <hip/hip_runtime.h>
#include <cstdint>
#include <cstddef>

#define NB 4096
#define FD 256

typedef __attribute__((ext_vector_type(4))) float f32x4;
typedef __attribute__((ext_vector_type(8))) short bf16x8;

__device__ __forceinline__ ushort f2bf(float f) {
  union { float f; uint32_t u; } v; v.f = f;
  uint32_t r = v.u + 0x7fffu + ((v.u >> 16) & 1u);
  return (ushort)(r >> 16);
}
__device__ __forceinline__ float bf2f(ushort b) {
  union { uint32_t u; float f; } v; v.u = ((uint32_t)b) << 16;
  return v.f;
}

__device__ __forceinline__ void gld16(const void* g, void* l) {
  __builtin_amdgcn_global_load_lds(
      (const __attribute__((address_space(1))) char*)g,
      (__attribute__((address_space(3))) char*)l, 16, 0, 0);
}

__device__ __forceinline__ float wave_reduce_sum(float v) {
#pragma unroll
  for (int off = 32; off >= 1; off >>= 1) v += __shfl_xor(v, off);
  return v;
}

// ---------------- rownorm ---------------------------------------------------
__global__ __launch_bounds__(256) void rownorm_kernel(
    const float* __restrict__ h, const float* __restrict__ x,
    const float* __restrict__ gamma, const float* __restrict__ beta,
    ushort* __restrict__ hnb, ushort* __restrict__ xnb, float* __restrict__ diag) {
  __shared__ float rA[4], rB[4], rC[4], rD[4];
  const int r = blockIdx.x, t = threadIdx.x, wid = t >> 6, lane = t & 63;
  const size_t base = (size_t)r * FD + t;
  const float hv = h[base], xv = x[base];
  float s1 = wave_reduce_sum(hv);
  float s2 = wave_reduce_sum(hv * hv);
  float a1 = wave_reduce_sum(fabsf(xv));
  float q1 = wave_reduce_sum(xv * xv);
  if (lane == 0) { rA[wid] = s1; rB[wid] = s2; rC[wid] = a1; rD[wid] = q1; }
  __syncthreads();
  const float S1 = rA[0] + rA[1] + rA[2] + rA[3];
  const float S2 = rB[0] + rB[1] + rB[2] + rB[3];
  const float L1 = rC[0] + rC[1] + rC[2] + rC[3];
  const float Q1 = rD[0] + rD[1] + rD[2] + rD[3];
  const float mu = S1 * (1.0f / FD);
  const float var = S2 * (1.0f / FD) - mu * mu;
  const float rstd = rsqrtf(var + 1e-5f);
  const float d = fmaxf(L1, 1e-12f), dinv = 1.0f / d;
  hnb[base] = f2bf((hv - mu) * rstd * gamma[t] + beta[t]);
  xnb[base] = f2bf(xv * dinv);
  if (t == 0) diag[r] = Q1 * dinv * dinv;
}

// ---------------- weight casts ---------------------------------------------
__global__ __launch_bounds__(256) void wcast_kernel(
    const float* __restrict__ w_k, const float* __restrict__ w_q,
    const float* __restrict__ w_v,
    ushort* __restrict__ wkb, ushort* __restrict__ wqb, ushort* __restrict__ wvb) {
  const int r = blockIdx.x, t = threadIdx.x;
  wkb[r * 256 + t] = f2bf(w_k[r * 256 + t]);
  wqb[r * 256 + t] = f2bf(w_q[r * 256 + t]);
  wvb[r * 320 + t] = f2bf(w_v[(size_t)r * 259 + t]);
  if (t < 64) {
    const int c = 256 + t;
    wvb[r * 320 + c] = (c < 259) ? f2bf(w_v[(size_t)r * 259 + c]) : (ushort)0;
  }
}

// ---------------- bf16 transpose (64x64 tiles) ------------------------------
__global__ __launch_bounds__(256) void transpose_kernel(
    const ushort* __restrict__ in, ushort* __restrict__ out, int R, int C) {
  __shared__ ushort tile[64][65];
  const int bc = blockIdx.x * 64, br = blockIdx.y * 64;
  const int t = threadIdx.x;
#pragma unroll
  for (int i = 0; i < 16; ++i) {
    const int idx = t + 256 * i;
    const int rr = idx >> 6, cc = idx & 63;
    tile[rr][cc] = in[(size_t)(br + rr) * C + bc + cc];
  }
  __syncthreads();
#pragma unroll
  for (int i = 0; i < 16; ++i) {
    const int idx = t + 256 * i;
    const int rr = idx >> 6, cc = idx & 63;
    out[(size_t)(bc + rr) * R + br + cc] = tile[cc][rr];
  }
}

// ---------------- colsum of xn ----------------------------------------------
__global__ __launch_bounds__(256) void colsum_kernel(
    const ushort* __restrict__ xnT, float* __restrict__ s) {
  __shared__ float red[4];
  const int f = blockIdx.x, t = threadIdx.x, wid = t >> 6, lane = t & 63;
  float a = 0.f;
#pragma unroll
  for (int i = 0; i < 16; ++i) a += bf2f(xnT[(size_t)f * NB + t + 256 * i]);
  a = wave_reduce_sum(a);
  if (lane == 0) red[wid] = a;
  __syncthreads();
  if (t == 0) s[f] = red[0] + red[1] + red[2] + red[3];
}

// ---------------- split-K 16-way reduce (Gram) ------------------------------
__global__ __launch_bounds__(256) void reduce16_kernel(
    const float* __restrict__ in, ushort* __restrict__ out) {
  const int idx = blockIdx.x * 256 + threadIdx.x;
  float a = 0.f;
#pragma unroll
  for (int z = 0; z < 16; ++z) a += in[(size_t)z * (FD * FD) + idx];
  out[idx] = f2bf(a);
}

// ---------------- rowsum: reduce 64 psums slices ----------------------------
__global__ __launch_bounds__(256) void rowsum_kernel(
    const float* __restrict__ psums, float* __restrict__ rowsum) {
  const int i = blockIdx.x * 256 + threadIdx.x;
  float s = 0.f;
#pragma unroll
  for (int z = 0; z < 64; ++z) s += psums[(size_t)z * NB + i];
  rowsum[i] = s;
}

// ---------------- hnsT = hnT * (1/rowsum[col]) ------------------------------
__global__ __launch_bounds__(256) void hns_kernel(
    const ushort* __restrict__ hnbT, const float* __restrict__ rowsum,
    ushort* __restrict__ hnsT) {
  const size_t idx = ((size_t)blockIdx.x * 256 + threadIdx.x) * 8;
  const int i0 = (int)(idx & (NB - 1));
  const uint4 c = *(const uint4*)(hnbT + idx);
  const float4 ra = *(const float4*)(rowsum + i0);
  const float4 rb = *(const float4*)(rowsum + i0 + 4);
  const uint32_t cw[4] = {c.x, c.y, c.z, c.w};
  const float rs[8] = {ra.x, ra.y, ra.z, ra.w, rb.x, rb.y, rb.z, rb.w};
  uint32_t ow[4];
#pragma unroll
  for (int j = 0; j < 4; ++j) {
    const float lo = bf2f((ushort)(cw[j] & 0xffffu)) / rs[j * 2];
    const float hi = bf2f((ushort)(cw[j] >> 16)) / rs[j * 2 + 1];
    ow[j] = (uint32_t)f2bf(lo) | ((uint32_t)f2bf(hi) << 16);
  }
  *(uint4*)(hnsT + idx) = make_uint4(ow[0], ow[1], ow[2], ow[3]);
}

// ---------------- stats -> haggp cols 256..319 ------------------------------
__global__ __launch_bounds__(64) void stats_kernel(
    const ushort* __restrict__ xnb, const float* __restrict__ t2,
    const float* __restrict__ s, const float* __restrict__ diag,
    ushort* __restrict__ haggp) {
  const int r = blockIdx.x, l = threadIdx.x;
  float rs = 0.f, rq = 0.f;
#pragma unroll
  for (int i = 0; i < 4; ++i) {
    const int f = l + 64 * i;
    const float xv = bf2f(xnb[(size_t)r * FD + f]);
    rs += xv * s[f];
    rq += xv * t2[(size_t)r * FD + f];
  }
  rs = wave_reduce_sum(rs);
  rq = wave_reduce_sum(rq);
  const float mean = rs * (1.0f / NB);
  const float var = (rq - (float)NB * mean * mean) * (1.0f / (NB - 1));
  const float sd = sqrtf(fmaxf(var, 0.f));
  ushort v = 0;
  if (l == 0) v = f2bf(diag[r]);
  else if (l == 1) v = f2bf(rs);
  else if (l == 2) v = f2bf(sd);
  haggp[(size_t)r * 320 + 256 + l] = v;
}

// ---------------- fused combine ---------------------------------------------
// out_x = mBx*rinv[row]*sum(px) + mAx*t2 + x
// haggp[:,0:256] = bf16(mBh*sum(ph) + mAh*t3)   (rinv already folded via hnsT)
__global__ __launch_bounds__(256) void combine_both_kernel(
    const ushort* __restrict__ px, const ushort* __restrict__ ph,
    const float* __restrict__ t2, const float* __restrict__ t3,
    const float* __restrict__ x, const float* __restrict__ rowsum,
    float* __restrict__ out_x, ushort* __restrict__ haggp,
    const float* __restrict__ mix) {
  const size_t NF = (size_t)NB * FD;
  const size_t idx = ((size_t)blockIdx.x * 256 + threadIdx.x) * 4;
  const float e0x = __expf(mix[0]), e1x = __expf(mix[2]);
  const float mAx = e0x / (e0x + e1x), mBx = e1x / (e0x + e1x);
  const float e0h = __expf(mix[1]), e1h = __expf(mix[3]);
  const float mAh = e0h / (e0h + e1h), mBh = e1h / (e0h + e1h);

  float ax[4] = {0.f, 0.f, 0.f, 0.f}, ah[4] = {0.f, 0.f, 0.f, 0.f};
#pragma unroll
  for (int z = 0; z < 8; ++z) {
    const ushort4 cx = *(const ushort4*)(px + (size_t)z * NF + idx);
    const ushort4 ch = *(const ushort4*)(ph + (size_t)z * NF + idx);
    ax[0] += bf2f(cx.x); ax[1] += bf2f(cx.y); ax[2] += bf2f(cx.z); ax[3] += bf2f(cx.w);
    ah[0] += bf2f(ch.x); ah[1] += bf2f(ch.y); ah[2] += bf2f(ch.z); ah[3] += bf2f(ch.w);
  }
  const size_t row = idx >> 8, col = idx & 255;
  const float rinv = 1.f / rowsum[row];
  const float sx = mBx * rinv;
  const float4 r2 = *(const float4*)(t2 + idx);
  const float4 r3 = *(const float4*)(t3 + idx);
  const float4 xr = *(const float4*)(x + idx);
  float4 ox;
  ox.x = sx * ax[0] + mAx * r2.x + xr.x;
  ox.y = sx * ax[1] + mAx * r2.y + xr.y;
  ox.z = sx * ax[2] + mAx * r2.z + xr.z;
  ox.w = sx * ax[3] + mAx * r2.w + xr.w;
  *(float4*)(out_x + idx) = ox;
  ushort4 oh;
  oh.x = f2bf(mBh * ah[0] + mAh * r3.x);
  oh.y = f2bf(mBh * ah[1] + mAh * r3.y);
  oh.z = f2bf(mBh * ah[2] + mAh * r3.z);
  oh.w = f2bf(mBh * ah[3] + mAh * r3.w);
  *(ushort4*)(haggp + row * 320 + col) = oh;
}

// ---------------- NT bf16 MFMA GEMM, 2-phase double-buffered ----------------
// C[i,j] = sum_k A[i,k]*B[j,k]
// EPI: 0 fp32*alpha | 1 bf16*alpha | 4 fp32 elu(acc)+R2
//      5 splitK fp32 partial | 6 splitK bf16 partial
//      7 E = bf16(exp(acc*alpha)) + per-(block,colhalf) row sums -> aux
template <int BM, int BN, int EPI>
__global__ __launch_bounds__(256) void gemm_nt(
    const ushort* __restrict__ A, int lda,
    const ushort* __restrict__ B, int ldb,
    void* __restrict__ Cp, int ldc, int K, float alpha,
    size_t pstride, const float* __restrict__ R2, float* __restrict__ aux) {
  constexpr int WAVES_N = (BM <= 32) ? 4 : 2;
  constexpr int WAVES_M = 4 / WAVES_N;
  constexpr int WM = BM / WAVES_M, WN = BN / WAVES_N;
  constexpr int MR = WM / 16, NR = WN / 16;
  __shared__ __align__(16) ushort At[2][BM][32];
  __shared__ __align__(16) ushort Bt[2][BN][32];
  const int tid = threadIdx.x;
  const int wave = tid >> 6, lane = tid & 63;
  const int wr = wave / WAVES_N, wc = wave % WAVES_N;
  const int bi = blockIdx.y * BM, bj = blockIdx.x * BN;
  const int fr = lane & 15, fq = lane >> 4;
  const int sub = lane >> 2, q = lane & 3;

  f32x4 acc[MR][NR];
#pragma unroll
  for (int m = 0; m < MR; ++m)
#pragma unroll
    for (int n = 0; n < NR; ++n) acc[m][n] = (f32x4){0.f, 0.f, 0.f, 0.f};

  const int kbase = (EPI == 5 || EPI == 6) ? (int)blockIdx.z * K : 0;
  const int kend = kbase + K;

  auto stage = [&](int bufi, int k0) {
    for (int c = wave; c < BM / 16; c += 4) {
      const int row = c * 16 + sub;
      const int qs = q ^ (row & 3);
      gld16(A + (size_t)(bi + row) * lda + k0 + qs * 8, &At[bufi][c * 16][0]);
    }
    for (int c = wave; c < BN / 16; c += 4) {
      const int row = c * 16 + sub;
      const int qs = q ^ (row & 3);
      gld16(B + (size_t)(bj + row) * ldb + k0 + qs * 8, &Bt[bufi][c * 16][0]);
    }
  };

  stage(0, kbase);
  __syncthreads();

  int cur = 0;
  for (int k0 = kbase; k0 < kend; k0 += 32) {
    if (k0 + 32 < kend) stage(cur ^ 1, k0 + 32);
    bf16x8 a[MR], b[NR];
#pragma unroll
    for (int m = 0; m < MR; ++m) {
      const int row = wr * WM + m * 16 + fr;
      a[m] = *(const bf16x8*)((const char*)&At[cur][row][0] + ((fq ^ (row & 3)) * 16));
    }
#pragma unroll
    for (int n = 0; n < NR; ++n) {
      const int row = wc * WN + n * 16 + fr;
      b[n] = *(const bf16x8*)((const char*)&Bt[cur][row][0] + ((fq ^ (row & 3)) * 16));
    }
#pragma unroll
    for (int m = 0; m < MR; ++m)
#pragma unroll
      for (int n = 0; n < NR; ++n)
        acc[m][n] = __builtin_amdgcn_mfma_f32_16x16x32_bf16(a[m], b[n], acc[m][n], 0, 0, 0);
    __syncthreads();
    cur ^= 1;
  }

  if (EPI == 7) {
    // E = bf16(exp(acc*alpha)); deterministic row partial sums into
    // aux[(blockIdx.x*2 + wc) * NB + row]
#pragma unroll
    for (int m = 0; m < MR; ++m) {
      float esum[4] = {0.f, 0.f, 0.f, 0.f};
#pragma unroll
      for (int n = 0; n < NR; ++n)
#pragma unroll
        for (int r = 0; r < 4; ++r) {
          const int row = bi + wr * WM + m * 16 + fq * 4 + r;
          const int col = bj + wc * WN + n * 16 + fr;
          const float e = __expf(acc[m][n][r] * alpha);
          ((ushort*)Cp)[(size_t)row * ldc + col] = f2bf(e);
          esum[r] += e;
        }
#pragma unroll
      for (int r = 0; r < 4; ++r) {
        float s = esum[r];
        s += __shfl_xor(s, 1); s += __shfl_xor(s, 2);
        s += __shfl_xor(s, 4); s += __shfl_xor(s, 8);
        if (fr == 0) {
          const int row = bi + wr * WM + m * 16 + fq * 4 + r;
          aux[(size_t)(blockIdx.x * 2 + wc) * NB + row] = s;
        }
      }
    }
    return;
  }

#pragma unroll
  for (int m = 0; m < MR; ++m)
#pragma unroll
    for (int n = 0; n < NR; ++n)
#pragma unroll
      for (int r = 0; r < 4; ++r) {
        const int row = bi + wr * WM + m * 16 + fq * 4 + r;
        const int col = bj + wc * WN + n * 16 + fr;
        const size_t ci = (size_t)row * ldc + col;
        const float v = acc[m][n][r];
        if (EPI == 0) ((float*)Cp)[ci] = v * alpha;
        else if (EPI == 1) ((ushort*)Cp)[ci] = f2bf(v * alpha);
        else if (EPI == 4) { const float e = (v > 0.f) ? v : expm1f(v); ((float*)Cp)[ci] = e + R2[(size_t)row * FD + col]; }
        else if (EPI == 5) ((float*)Cp)[(size_t)blockIdx.z * pstride + ci] = v;
        else if (EPI == 6) ((ushort*)Cp)[(size_t)blockIdx.z * pstride + ci] = f2bf(v);
      }
}

// ---------------------------------------------------------------------------
extern "C" void kernel_launch(void* const* d_in, const int* in_sizes, int n_in,
                              void* d_out, int out_size, void* d_ws, size_t ws_size,
                              hipStream_t stream) {
  const float* h      = (const float*)d_in[0];
  const float* x      = (const float*)d_in[1];
  const float* w_k    = (const float*)d_in[2];
  const float* w_q    = (const float*)d_in[3];
  const float* w_v    = (const float*)d_in[4];
  const float* mixing = (const float*)d_in[5];
  const float* gamma  = (const float*)d_in[6];
  const float* beta   = (const float*)d_in[7];

  float* out_h = (float*)d_out;
  float* out_x = out_h + (size_t)NB * FD;

  char* w = (char*)d_ws;
  ushort* E     = (ushort*)(w + 0);           // 32MB [NB,NB] bf16 exp(scores)
  ushort* px    = (ushort*)(w + 33554432);    // 16MB splitK partials
  ushort* ph    = (ushort*)(w + 50331648);    // 16MB
  ushort* ET    = (ushort*)(w + 67108864);    // 32MB [NB,NB]
  ushort* hnb   = (ushort*)(w + 100663296);
  ushort* xnb   = (ushort*)(w + 102760448);
  ushort* hnbT  = (ushort*)(w + 104857600);
  ushort* xnbT  = (ushort*)(w + 106954752);
  ushort* kb    = (ushort*)(w + 109051904);
  ushort* qb    = (ushort*)(w + 111149056);
  ushort* haggp = (ushort*)(w + 113246208);   // [NB,320] bf16
  ushort* wkb   = (ushort*)(w + 115867648);
  ushort* wqb   = (ushort*)(w + 115998720);
  ushort* wvb   = (ushort*)(w + 116129792);   // [FD,320]
  ushort* Gb    = (ushort*)(w + 116293632);
  ushort* M2b   = (ushort*)(w + 116424704);
  float*  diag  = (float*)(w + 116555776);
  float*  sv    = (float*)(w + 116572160);
  float*  t2    = (float*)(w + 116573184);    // 4MB
  float*  t3    = (float*)(w + 120767488);    // 4MB
  float*  psums = (float*)(w + 124961792);    // 1MB  [64][NB]
  float*  rowsum= (float*)(w + 126010368);    // 16KB
  ushort* hnsT  = (ushort*)(w + 126026752);   // 2MB  [FD,NB]
  // aliases (disjoint lifetimes): Gram partials live in ET region, dead
  // before the E->ET transpose runs.
  float*  Gp  = (float*)(w + 67108864);
  float*  M2p = (float*)(w + 71303168);

  rownorm_kernel<<<NB, 256, 0, stream>>>(h, x, gamma, beta, hnb, xnb, diag);
  wcast_kernel<<<FD, 256, 0, stream>>>(w_k, w_q, w_v, wkb, wqb, wvb);
  transpose_kernel<<<dim3(FD / 64, NB / 64), 256, 0, stream>>>(xnb, xnbT, NB, FD);
  transpose_kernel<<<dim3(FD / 64, NB / 64), 256, 0, stream>>>(hnb, hnbT, NB, FD);
  colsum_kernel<<<FD, 256, 0, stream>>>(xnbT, sv);

  // projections
  gemm_nt<64, 64, 1><<<dim3(FD / 64, NB / 64), 256, 0, stream>>>(
      hnb, FD, wkb, FD, kb, FD, FD, 1.f, 0, nullptr, nullptr);
  gemm_nt<64, 64, 1><<<dim3(FD / 64, NB / 64), 256, 0, stream>>>(
      hnb, FD, wqb, FD, qb, FD, FD, 1.f, 0, nullptr, nullptr);

  // Gram matrices (split-K 16, fp32 partials)
  gemm_nt<64, 64, 5><<<dim3(4, 4, 16), 256, 0, stream>>>(
      xnbT, NB, xnbT, NB, Gp, FD, NB / 16, 1.f, (size_t)FD * FD, nullptr, nullptr);
  gemm_nt<64, 64, 5><<<dim3(4, 4, 16), 256, 0, stream>>>(
      hnbT, NB, xnbT, NB, M2p, FD, NB / 16, 1.f, (size_t)FD * FD, nullptr, nullptr);
  reduce16_kernel<<<FD * FD / 256, 256, 0, stream>>>(Gp, Gb);
  reduce16_kernel<<<FD * FD / 256, 256, 0, stream>>>(M2p, M2b);

  // E = exp((k @ q^T)/16), psums = deterministic row partial sums
  gemm_nt<128, 128, 7><<<dim3(NB / 128, NB / 128), 256, 0, stream>>>(
      kb, FD, qb, FD, E, NB, FD, 0.0625f, 0, nullptr, psums);
  rowsum_kernel<<<NB / 256, 256, 0, stream>>>(psums, rowsum);
  transpose_kernel<<<dim3(NB / 64, NB / 64), 256, 0, stream>>>(E, ET, NB, NB);
  hns_kernel<<<(FD * NB) / (256 * 8), 256, 0, stream>>>(hnbT, rowsum, hnsT);

  // t2 = xn@G, t3 = xn@M2
  gemm_nt<64, 64, 0><<<dim3(FD / 64, NB / 64), 256, 0, stream>>>(
      xnb, FD, Gb, FD, t2, FD, FD, 1.f, 0, nullptr, nullptr);
  gemm_nt<64, 64, 0><<<dim3(FD / 64, NB / 64), 256, 0, stream>>>(
      xnb, FD, M2b, FD, t3, FD, FD, 1.f, 0, nullptr, nullptr);
  stats_kernel<<<NB, 64, 0, stream>>>(xnb, t2, sv, diag, haggp);

  // aggregation partials (split-K 8, bf16 partials)
  gemm_nt<32, 128, 6><<<dim3(FD / 128, NB / 32, 8), 256, 0, stream>>>(
      E, NB, xnbT, NB, px, FD, NB / 8, 1.f, (size_t)NB * FD, nullptr, nullptr);
  gemm_nt<32, 128, 6><<<dim3(FD / 128, NB / 32, 8), 256, 0, stream>>>(
      ET, NB, hnsT, NB, ph, FD, NB / 8, 1.f, (size_t)NB * FD, nullptr, nullptr);

  // fused combine: x_out and haggp[:,0:256]
  combine_both_kernel<<<NB * FD / 1024, 256, 0, stream>>>(
      px, ph, t2, t3, x, rowsum, out_x, haggp, mixing);

  // h_out = elu(concat(hagg,stats) @ w_v^T) + h
  gemm_nt<64, 64, 4><<<dim3(FD / 64, NB / 64), 256, 0, stream>>>(
      haggp, 320, wvb, 320, out_h, FD, 320, 1.f, 0, h, nullptr);
}

// Round 6
// 162.826 us; speedup vs baseline: 1.1713x; 1.1713x over previous
//
#include <hip/hip_runtime.h>
#include <cstdint>
#include <cstddef>

#define NB 4096
#define FD 256

typedef __attribute__((ext_vector_type(4))) float f32x4;
typedef __attribute__((ext_vector_type(8))) short bf16x8;

__device__ __forceinline__ ushort f2bf(float f) {
  union { float f; uint32_t u; } v; v.f = f;
  uint32_t r = v.u + 0x7fffu + ((v.u >> 16) & 1u);
  return (ushort)(r >> 16);
}
__device__ __forceinline__ float bf2f(ushort b) {
  union { uint32_t u; float f; } v; v.u = ((uint32_t)b) << 16;
  return v.f;
}

__device__ __forceinline__ void gld16(const void* g, void* l) {
  __builtin_amdgcn_global_load_lds(
      (const __attribute__((address_space(1))) char*)g,
      (__attribute__((address_space(3))) char*)l, 16, 0, 0);
}

__device__ __forceinline__ float wave_reduce_sum(float v) {
#pragma unroll
  for (int off = 32; off >= 1; off >>= 1) v += __shfl_xor(v, off);
  return v;
}
__device__ __forceinline__ float wave_reduce_max(float v) {
#pragma unroll
  for (int off = 32; off >= 1; off >>= 1) v = fmaxf(v, __shfl_xor(v, off));
  return v;
}

// ---------------- rownorm ---------------------------------------------------
__global__ __launch_bounds__(256) void rownorm_kernel(
    const float* __restrict__ h, const float* __restrict__ x,
    const float* __restrict__ gamma, const float* __restrict__ beta,
    ushort* __restrict__ hnb, ushort* __restrict__ xnb, float* __restrict__ diag) {
  __shared__ float rA[4], rB[4], rC[4], rD[4];
  const int r = blockIdx.x, t = threadIdx.x, wid = t >> 6, lane = t & 63;
  const size_t base = (size_t)r * FD + t;
  const float hv = h[base], xv = x[base];
  float s1 = wave_reduce_sum(hv);
  float s2 = wave_reduce_sum(hv * hv);
  float a1 = wave_reduce_sum(fabsf(xv));
  float q1 = wave_reduce_sum(xv * xv);
  if (lane == 0) { rA[wid] = s1; rB[wid] = s2; rC[wid] = a1; rD[wid] = q1; }
  __syncthreads();
  const float S1 = rA[0] + rA[1] + rA[2] + rA[3];
  const float S2 = rB[0] + rB[1] + rB[2] + rB[3];
  const float L1 = rC[0] + rC[1] + rC[2] + rC[3];
  const float Q1 = rD[0] + rD[1] + rD[2] + rD[3];
  const float mu = S1 * (1.0f / FD);
  const float var = S2 * (1.0f / FD) - mu * mu;
  const float rstd = rsqrtf(var + 1e-5f);
  const float d = fmaxf(L1, 1e-12f), dinv = 1.0f / d;
  hnb[base] = f2bf((hv - mu) * rstd * gamma[t] + beta[t]);
  xnb[base] = f2bf(xv * dinv);
  if (t == 0) diag[r] = Q1 * dinv * dinv;
}

// ---------------- weight casts ---------------------------------------------
__global__ __launch_bounds__(256) void wcast_kernel(
    const float* __restrict__ w_k, const float* __restrict__ w_q,
    const float* __restrict__ w_v,
    ushort* __restrict__ wkb, ushort* __restrict__ wqb, ushort* __restrict__ wvb) {
  const int r = blockIdx.x, t = threadIdx.x;
  wkb[r * 256 + t] = f2bf(w_k[r * 256 + t]);
  wqb[r * 256 + t] = f2bf(w_q[r * 256 + t]);
  wvb[r * 320 + t] = f2bf(w_v[(size_t)r * 259 + t]);
  if (t < 64) {
    const int c = 256 + t;
    wvb[r * 320 + c] = (c < 259) ? f2bf(w_v[(size_t)r * 259 + c]) : (ushort)0;
  }
}

// ---------------- bf16 transpose (64x64 tiles) ------------------------------
__global__ __launch_bounds__(256) void transpose_kernel(
    const ushort* __restrict__ in, ushort* __restrict__ out, int R, int C) {
  __shared__ ushort tile[64][65];
  const int bc = blockIdx.x * 64, br = blockIdx.y * 64;
  const int t = threadIdx.x;
#pragma unroll
  for (int i = 0; i < 16; ++i) {
    const int idx = t + 256 * i;
    const int rr = idx >> 6, cc = idx & 63;
    tile[rr][cc] = in[(size_t)(br + rr) * C + bc + cc];
  }
  __syncthreads();
#pragma unroll
  for (int i = 0; i < 16; ++i) {
    const int idx = t + 256 * i;
    const int rr = idx >> 6, cc = idx & 63;
    out[(size_t)(bc + rr) * R + br + cc] = tile[cc][rr];
  }
}

// ---------------- colsum of xn ----------------------------------------------
__global__ __launch_bounds__(256) void colsum_kernel(
    const ushort* __restrict__ xnT, float* __restrict__ s) {
  __shared__ float red[4];
  const int f = blockIdx.x, t = threadIdx.x, wid = t >> 6, lane = t & 63;
  float a = 0.f;
#pragma unroll
  for (int i = 0; i < 16; ++i) a += bf2f(xnT[(size_t)f * NB + t + 256 * i]);
  a = wave_reduce_sum(a);
  if (lane == 0) red[wid] = a;
  __syncthreads();
  if (t == 0) s[f] = red[0] + red[1] + red[2] + red[3];
}

// ---------------- split-K 16-way reduce (Gram) ------------------------------
__global__ __launch_bounds__(256) void reduce16_kernel(
    const float* __restrict__ in, ushort* __restrict__ out) {
  const int idx = blockIdx.x * 256 + threadIdx.x;
  float a = 0.f;
#pragma unroll
  for (int z = 0; z < 16; ++z) a += in[(size_t)z * (FD * FD) + idx];
  out[idx] = f2bf(a);
}

// ---------------- row softmax: S bf16 -> P bf16 -----------------------------
__global__ __launch_bounds__(256) void softmax_kernel(
    const ushort* __restrict__ S, ushort* __restrict__ P) {
  __shared__ float red[4];
  const int r = blockIdx.x, t = threadIdx.x, wid = t >> 6, lane = t & 63;
  const uint4* Sr = (const uint4*)(S + (size_t)r * NB);
  float v[16];
  float lmax = -1e30f;
#pragma unroll
  for (int i = 0; i < 2; ++i) {
    const uint4 c = Sr[t + 256 * i];
    const uint32_t w4[4] = {c.x, c.y, c.z, c.w};
#pragma unroll
    for (int j = 0; j < 4; ++j) {
      v[i * 8 + j * 2]     = bf2f((ushort)(w4[j] & 0xffffu));
      v[i * 8 + j * 2 + 1] = bf2f((ushort)(w4[j] >> 16));
    }
  }
#pragma unroll
  for (int u = 0; u < 16; ++u) lmax = fmaxf(lmax, v[u]);
  lmax = wave_reduce_max(lmax);
  if (lane == 0) red[wid] = lmax;
  __syncthreads();
  const float gmax = fmaxf(fmaxf(red[0], red[1]), fmaxf(red[2], red[3]));
  __syncthreads();
  float lsum = 0.f;
#pragma unroll
  for (int u = 0; u < 16; ++u) { v[u] = __expf(v[u] - gmax); lsum += v[u]; }
  lsum = wave_reduce_sum(lsum);
  if (lane == 0) red[wid] = lsum;
  __syncthreads();
  const float pinv = 1.f / (red[0] + red[1] + red[2] + red[3]);
  uint4* Pr = (uint4*)(P + (size_t)r * NB);
#pragma unroll
  for (int i = 0; i < 2; ++i) {
    uint4 o;
    o.x = (uint32_t)f2bf(v[i*8+0] * pinv) | ((uint32_t)f2bf(v[i*8+1] * pinv) << 16);
    o.y = (uint32_t)f2bf(v[i*8+2] * pinv) | ((uint32_t)f2bf(v[i*8+3] * pinv) << 16);
    o.z = (uint32_t)f2bf(v[i*8+4] * pinv) | ((uint32_t)f2bf(v[i*8+5] * pinv) << 16);
    o.w = (uint32_t)f2bf(v[i*8+6] * pinv) | ((uint32_t)f2bf(v[i*8+7] * pinv) << 16);
    Pr[t + 256 * i] = o;
  }
}

// ---------------- stats -> haggp cols 256..319 ------------------------------
__global__ __launch_bounds__(64) void stats_kernel(
    const ushort* __restrict__ xnb, const float* __restrict__ t2,
    const float* __restrict__ s, const float* __restrict__ diag,
    ushort* __restrict__ haggp) {
  const int r = blockIdx.x, l = threadIdx.x;
  float rs = 0.f, rq = 0.f;
#pragma unroll
  for (int i = 0; i < 4; ++i) {
    const int f = l + 64 * i;
    const float xv = bf2f(xnb[(size_t)r * FD + f]);
    rs += xv * s[f];
    rq += xv * t2[(size_t)r * FD + f];
  }
  rs = wave_reduce_sum(rs);
  rq = wave_reduce_sum(rq);
  const float mean = rs * (1.0f / NB);
  const float var = (rq - (float)NB * mean * mean) * (1.0f / (NB - 1));
  const float sd = sqrtf(fmaxf(var, 0.f));
  ushort v = 0;
  if (l == 0) v = f2bf(diag[r]);
  else if (l == 1) v = f2bf(rs);
  else if (l == 2) v = f2bf(sd);
  haggp[(size_t)r * 320 + 256 + l] = v;
}

// ---------------- fused combine: 8 bf16 partials each + mixing + residual ---
// out_x = mBx*sum(px) + mAx*t2 + x ;  haggp[:,0:256] = bf16(mBh*sum(ph) + mAh*t3)
__global__ __launch_bounds__(256) void combine_both_kernel(
    const ushort* __restrict__ px, const ushort* __restrict__ ph,
    const float* __restrict__ t2, const float* __restrict__ t3,
    const float* __restrict__ x, float* __restrict__ out_x,
    ushort* __restrict__ haggp, const float* __restrict__ mix) {
  const size_t NF = (size_t)NB * FD;
  const size_t idx = ((size_t)blockIdx.x * 256 + threadIdx.x) * 4;
  const float e0x = __expf(mix[0]), e1x = __expf(mix[2]);
  const float mAx = e0x / (e0x + e1x), mBx = e1x / (e0x + e1x);
  const float e0h = __expf(mix[1]), e1h = __expf(mix[3]);
  const float mAh = e0h / (e0h + e1h), mBh = e1h / (e0h + e1h);

  float ax[4] = {0.f, 0.f, 0.f, 0.f}, ah[4] = {0.f, 0.f, 0.f, 0.f};
#pragma unroll
  for (int z = 0; z < 8; ++z) {
    const ushort4 cx = *(const ushort4*)(px + (size_t)z * NF + idx);
    const ushort4 ch = *(const ushort4*)(ph + (size_t)z * NF + idx);
    ax[0] += bf2f(cx.x); ax[1] += bf2f(cx.y); ax[2] += bf2f(cx.z); ax[3] += bf2f(cx.w);
    ah[0] += bf2f(ch.x); ah[1] += bf2f(ch.y); ah[2] += bf2f(ch.z); ah[3] += bf2f(ch.w);
  }
  const float4 r2 = *(const float4*)(t2 + idx);
  const float4 r3 = *(const float4*)(t3 + idx);
  const float4 xr = *(const float4*)(x + idx);
  float4 ox;
  ox.x = mBx * ax[0] + mAx * r2.x + xr.x;
  ox.y = mBx * ax[1] + mAx * r2.y + xr.y;
  ox.z = mBx * ax[2] + mAx * r2.z + xr.z;
  ox.w = mBx * ax[3] + mAx * r2.w + xr.w;
  *(float4*)(out_x + idx) = ox;
  const size_t row = idx >> 8, col = idx & 255;
  ushort4 oh;
  oh.x = f2bf(mBh * ah[0] + mAh * r3.x);
  oh.y = f2bf(mBh * ah[1] + mAh * r3.y);
  oh.z = f2bf(mBh * ah[2] + mAh * r3.z);
  oh.w = f2bf(mBh * ah[3] + mAh * r3.w);
  *(ushort4*)(haggp + row * 320 + col) = oh;
}

// ---------------- NT bf16 MFMA GEMM, 2-phase double-buffered ----------------
// C[i,j] = sum_k A[i,k]*B[j,k]
// EPI: 0 fp32*alpha | 1 bf16*alpha | 4 fp32 elu(acc)+R2
//      5 splitK fp32 partial | 6 splitK bf16 partial
// LDS granule swizzle: slot(row,q) holds global granule (q ^ (row&3)); applied
// to BOTH the gld16 source address and the ds_read offset (both-sides rule).
template <int BM, int BN, int EPI>
__global__ __launch_bounds__(256) void gemm_nt(
    const ushort* __restrict__ A, int lda,
    const ushort* __restrict__ B, int ldb,
    void* __restrict__ Cp, int ldc, int K, float alpha,
    size_t pstride, const float* __restrict__ R2) {
  constexpr int WAVES_N = (BM <= 32) ? 4 : 2;
  constexpr int WAVES_M = 4 / WAVES_N;
  constexpr int WM = BM / WAVES_M, WN = BN / WAVES_N;
  constexpr int MR = WM / 16, NR = WN / 16;
  __shared__ __align__(16) ushort At[2][BM][32];
  __shared__ __align__(16) ushort Bt[2][BN][32];
  const int tid = threadIdx.x;
  const int wave = tid >> 6, lane = tid & 63;
  const int wr = wave / WAVES_N, wc = wave % WAVES_N;
  const int bi = blockIdx.y * BM, bj = blockIdx.x * BN;
  const int fr = lane & 15, fq = lane >> 4;
  const int sub = lane >> 2, q = lane & 3;

  f32x4 acc[MR][NR];
#pragma unroll
  for (int m = 0; m < MR; ++m)
#pragma unroll
    for (int n = 0; n < NR; ++n) acc[m][n] = (f32x4){0.f, 0.f, 0.f, 0.f};

  const int kbase = (EPI >= 5) ? (int)blockIdx.z * K : 0;
  const int kend = kbase + K;

  // stage one 32-wide k-tile into buffer `bufi` (source pre-swizzled)
  auto stage = [&](int bufi, int k0) {
    for (int c = wave; c < BM / 16; c += 4) {
      const int row = c * 16 + sub;
      const int qs = q ^ (row & 3);
      gld16(A + (size_t)(bi + row) * lda + k0 + qs * 8, &At[bufi][c * 16][0]);
    }
    for (int c = wave; c < BN / 16; c += 4) {
      const int row = c * 16 + sub;
      const int qs = q ^ (row & 3);
      gld16(B + (size_t)(bj + row) * ldb + k0 + qs * 8, &Bt[bufi][c * 16][0]);
    }
  };

  stage(0, kbase);
  __syncthreads();

  int cur = 0;
  for (int k0 = kbase; k0 < kend; k0 += 32) {
    if (k0 + 32 < kend) stage(cur ^ 1, k0 + 32);  // prefetch next tile
    bf16x8 a[MR], b[NR];
#pragma unroll
    for (int m = 0; m < MR; ++m) {
      const int row = wr * WM + m * 16 + fr;
      a[m] = *(const bf16x8*)((const char*)&At[cur][row][0] + ((fq ^ (row & 3)) * 16));
    }
#pragma unroll
    for (int n = 0; n < NR; ++n) {
      const int row = wc * WN + n * 16 + fr;
      b[n] = *(const bf16x8*)((const char*)&Bt[cur][row][0] + ((fq ^ (row & 3)) * 16));
    }
#pragma unroll
    for (int m = 0; m < MR; ++m)
#pragma unroll
      for (int n = 0; n < NR; ++n)
        acc[m][n] = __builtin_amdgcn_mfma_f32_16x16x32_bf16(a[m], b[n], acc[m][n], 0, 0, 0);
    __syncthreads();  // drains vmcnt (prefetch landed) + lgkm; next iter reads cur^1
    cur ^= 1;
  }

#pragma unroll
  for (int m = 0; m < MR; ++m)
#pragma unroll
    for (int n = 0; n < NR; ++n)
#pragma unroll
      for (int r = 0; r < 4; ++r) {
        const int row = bi + wr * WM + m * 16 + fq * 4 + r;
        const int col = bj + wc * WN + n * 16 + fr;
        const size_t ci = (size_t)row * ldc + col;
        const float v = acc[m][n][r];
        if (EPI == 0) ((float*)Cp)[ci] = v * alpha;
        else if (EPI == 1) ((ushort*)Cp)[ci] = f2bf(v * alpha);
        else if (EPI == 4) { const float e = (v > 0.f) ? v : expm1f(v); ((float*)Cp)[ci] = e + R2[(size_t)row * FD + col]; }
        else if (EPI == 5) ((float*)Cp)[(size_t)blockIdx.z * pstride + ci] = v;
        else if (EPI == 6) ((ushort*)Cp)[(size_t)blockIdx.z * pstride + ci] = f2bf(v);
      }
}

// ---------------------------------------------------------------------------
extern "C" void kernel_launch(void* const* d_in, const int* in_sizes, int n_in,
                              void* d_out, int out_size, void* d_ws, size_t ws_size,
                              hipStream_t stream) {
  const float* h      = (const float*)d_in[0];
  const float* x      = (const float*)d_in[1];
  const float* w_k    = (const float*)d_in[2];
  const float* w_q    = (const float*)d_in[3];
  const float* w_v    = (const float*)d_in[4];
  const float* mixing = (const float*)d_in[5];
  const float* gamma  = (const float*)d_in[6];
  const float* beta   = (const float*)d_in[7];

  float* out_h = (float*)d_out;
  float* out_x = out_h + (size_t)NB * FD;

  char* w = (char*)d_ws;
  ushort* S     = (ushort*)(w + 0);           // 32MB [NB,NB] bf16 scores
  ushort* P     = (ushort*)(w + 33554432);    // 32MB
  ushort* PT    = (ushort*)(w + 67108864);    // 32MB
  ushort* hnb   = (ushort*)(w + 100663296);
  ushort* xnb   = (ushort*)(w + 102760448);
  ushort* hnbT  = (ushort*)(w + 104857600);
  ushort* xnbT  = (ushort*)(w + 106954752);
  ushort* kb    = (ushort*)(w + 109051904);
  ushort* qb    = (ushort*)(w + 111149056);
  ushort* haggp = (ushort*)(w + 113246208);   // [NB,320] bf16
  ushort* wkb   = (ushort*)(w + 115867648);
  ushort* wqb   = (ushort*)(w + 115998720);
  ushort* wvb   = (ushort*)(w + 116129792);   // [FD,320]
  ushort* Gb    = (ushort*)(w + 116293632);
  ushort* M2b   = (ushort*)(w + 116424704);
  float*  diag  = (float*)(w + 116555776);
  float*  sv    = (float*)(w + 116572160);
  float*  t2    = (float*)(w + 116573184);    // 4MB
  float*  t3    = (float*)(w + 120767488);    // 4MB
  // aliases (disjoint lifetimes):
  float*  Gp  = (float*)(w + 67108864);       // in PT region, dead before PT
  float*  M2p = (float*)(w + 71303168);
  ushort* px  = (ushort*)(w + 0);             // 16MB, in S region (S dead after softmax)
  ushort* ph  = (ushort*)(w + 16777216);      // 16MB

  rownorm_kernel<<<NB, 256, 0, stream>>>(h, x, gamma, beta, hnb, xnb, diag);
  wcast_kernel<<<FD, 256, 0, stream>>>(w_k, w_q, w_v, wkb, wqb, wvb);
  transpose_kernel<<<dim3(FD / 64, NB / 64), 256, 0, stream>>>(xnb, xnbT, NB, FD);
  transpose_kernel<<<dim3(FD / 64, NB / 64), 256, 0, stream>>>(hnb, hnbT, NB, FD);
  colsum_kernel<<<FD, 256, 0, stream>>>(xnbT, sv);

  // projections
  gemm_nt<64, 64, 1><<<dim3(FD / 64, NB / 64), 256, 0, stream>>>(
      hnb, FD, wkb, FD, kb, FD, FD, 1.f, 0, nullptr);
  gemm_nt<64, 64, 1><<<dim3(FD / 64, NB / 64), 256, 0, stream>>>(
      hnb, FD, wqb, FD, qb, FD, FD, 1.f, 0, nullptr);

  // Gram matrices (split-K 16, fp32 partials)
  gemm_nt<64, 64, 5><<<dim3(4, 4, 16), 256, 0, stream>>>(
      xnbT, NB, xnbT, NB, Gp, FD, NB / 16, 1.f, (size_t)FD * FD, nullptr);
  gemm_nt<64, 64, 5><<<dim3(4, 4, 16), 256, 0, stream>>>(
      hnbT, NB, xnbT, NB, M2p, FD, NB / 16, 1.f, (size_t)FD * FD, nullptr);
  reduce16_kernel<<<FD * FD / 256, 256, 0, stream>>>(Gp, Gb);
  reduce16_kernel<<<FD * FD / 256, 256, 0, stream>>>(M2p, M2b);

  // S = bf16((k @ q^T) / 16)
  gemm_nt<128, 128, 1><<<dim3(NB / 128, NB / 128), 256, 0, stream>>>(
      kb, FD, qb, FD, S, NB, FD, 0.0625f, 0, nullptr);
  softmax_kernel<<<NB, 256, 0, stream>>>(S, P);
  transpose_kernel<<<dim3(NB / 64, NB / 64), 256, 0, stream>>>(P, PT, NB, NB);

  // t2 = xn@G, t3 = xn@M2
  gemm_nt<64, 64, 0><<<dim3(FD / 64, NB / 64), 256, 0, stream>>>(
      xnb, FD, Gb, FD, t2, FD, FD, 1.f, 0, nullptr);
  gemm_nt<64, 64, 0><<<dim3(FD / 64, NB / 64), 256, 0, stream>>>(
      xnb, FD, M2b, FD, t3, FD, FD, 1.f, 0, nullptr);
  stats_kernel<<<NB, 64, 0, stream>>>(xnb, t2, sv, diag, haggp);

  // aggregation partials: 128x128 tiles, split-K 8 (m97-shape, 512 blocks)
  gemm_nt<128, 128, 6><<<dim3(FD / 128, NB / 128, 8), 256, 0, stream>>>(
      P, NB, xnbT, NB, px, FD, NB / 8, 1.f, (size_t)NB * FD, nullptr);
  gemm_nt<128, 128, 6><<<dim3(FD / 128, NB / 128, 8), 256, 0, stream>>>(
      PT, NB, hnbT, NB, ph, FD, NB / 8, 1.f, (size_t)NB * FD, nullptr);

  // fused combine: x_out and haggp[:,0:256]
  combine_both_kernel<<<NB * FD / 1024, 256, 0, stream>>>(
      px, ph, t2, t3, x, out_x, haggp, mixing);

  // h_out = elu(concat(hagg,stats) @ w_v^T) + h
  gemm_nt<64, 64, 4><<<dim3(FD / 64, NB / 64), 256, 0, stream>>>(
      haggp, 320, wvb, 320, out_h, FD, 320, 1.f, 0, h);
}

// Round 7
// 147.465 us; speedup vs baseline: 1.2933x; 1.1042x over previous
//
#include <hip/hip_runtime.h>
#include <cstdint>
#include <cstddef>

#define NB 4096
#define FD 256

typedef __attribute__((ext_vector_type(4))) float f32x4;
typedef __attribute__((ext_vector_type(8))) short bf16x8;

__device__ __forceinline__ ushort f2bf(float f) {
  union { float f; uint32_t u; } v; v.f = f;
  uint32_t r = v.u + 0x7fffu + ((v.u >> 16) & 1u);
  return (ushort)(r >> 16);
}
__device__ __forceinline__ float bf2f(ushort b) {
  union { uint32_t u; float f; } v; v.u = ((uint32_t)b) << 16;
  return v.f;
}

__device__ __forceinline__ void gld16(const void* g, void* l) {
  __builtin_amdgcn_global_load_lds(
      (const __attribute__((address_space(1))) char*)g,
      (__attribute__((address_space(3))) char*)l, 16, 0, 0);
}

__device__ __forceinline__ float wave_reduce_sum(float v) {
#pragma unroll
  for (int off = 32; off >= 1; off >>= 1) v += __shfl_xor(v, off);
  return v;
}
__device__ __forceinline__ float wave_reduce_max(float v) {
#pragma unroll
  for (int off = 32; off >= 1; off >>= 1) v = fmaxf(v, __shfl_xor(v, off));
  return v;
}

// ---------------- rownorm ---------------------------------------------------
__global__ __launch_bounds__(256) void rownorm_kernel(
    const float* __restrict__ h, const float* __restrict__ x,
    const float* __restrict__ gamma, const float* __restrict__ beta,
    ushort* __restrict__ hnb, ushort* __restrict__ xnb, float* __restrict__ diag) {
  __shared__ float rA[4], rB[4], rC[4], rD[4];
  const int r = blockIdx.x, t = threadIdx.x, wid = t >> 6, lane = t & 63;
  const size_t base = (size_t)r * FD + t;
  const float hv = h[base], xv = x[base];
  float s1 = wave_reduce_sum(hv);
  float s2 = wave_reduce_sum(hv * hv);
  float a1 = wave_reduce_sum(fabsf(xv));
  float q1 = wave_reduce_sum(xv * xv);
  if (lane == 0) { rA[wid] = s1; rB[wid] = s2; rC[wid] = a1; rD[wid] = q1; }
  __syncthreads();
  const float S1 = rA[0] + rA[1] + rA[2] + rA[3];
  const float S2 = rB[0] + rB[1] + rB[2] + rB[3];
  const float L1 = rC[0] + rC[1] + rC[2] + rC[3];
  const float Q1 = rD[0] + rD[1] + rD[2] + rD[3];
  const float mu = S1 * (1.0f / FD);
  const float var = S2 * (1.0f / FD) - mu * mu;
  const float rstd = rsqrtf(var + 1e-5f);
  const float d = fmaxf(L1, 1e-12f), dinv = 1.0f / d;
  hnb[base] = f2bf((hv - mu) * rstd * gamma[t] + beta[t]);
  xnb[base] = f2bf(xv * dinv);
  if (t == 0) diag[r] = Q1 * dinv * dinv;
}

// ---------------- weight casts ----------------------------------------------
// wkqb [512][256] = [w_k; w_q]; wvAb [256][256] = w_v[:,0:256];
// wvbT3 [3][256] fp32: wvbT3[s][f] = w_v[f][256+s]
__global__ __launch_bounds__(256) void wcast_kernel(
    const float* __restrict__ w_k, const float* __restrict__ w_q,
    const float* __restrict__ w_v,
    ushort* __restrict__ wkqb, ushort* __restrict__ wvAb,
    float* __restrict__ wvbT3) {
  const int r = blockIdx.x, t = threadIdx.x;
  wkqb[r * 256 + t] = f2bf(w_k[r * 256 + t]);
  wkqb[(256 + r) * 256 + t] = f2bf(w_q[r * 256 + t]);
  wvAb[r * 256 + t] = f2bf(w_v[(size_t)r * 259 + t]);
  if (t < 3) wvbT3[t * 256 + r] = w_v[(size_t)r * 259 + 256 + t];
}

// ---------------- bf16 transpose (64x64 tiles) ------------------------------
__global__ __launch_bounds__(256) void transpose_kernel(
    const ushort* __restrict__ in, ushort* __restrict__ out, int R, int C) {
  __shared__ ushort tile[64][65];
  const int bc = blockIdx.x * 64, br = blockIdx.y * 64;
  const int t = threadIdx.x;
#pragma unroll
  for (int i = 0; i < 16; ++i) {
    const int idx = t + 256 * i;
    const int rr = idx >> 6, cc = idx & 63;
    tile[rr][cc] = in[(size_t)(br + rr) * C + bc + cc];
  }
  __syncthreads();
#pragma unroll
  for (int i = 0; i < 16; ++i) {
    const int idx = t + 256 * i;
    const int rr = idx >> 6, cc = idx & 63;
    out[(size_t)(bc + rr) * R + br + cc] = tile[cc][rr];
  }
}

// ---------------- colsum of xn ----------------------------------------------
__global__ __launch_bounds__(256) void colsum_kernel(
    const ushort* __restrict__ xnT, float* __restrict__ s) {
  __shared__ float red[4];
  const int f = blockIdx.x, t = threadIdx.x, wid = t >> 6, lane = t & 63;
  float a = 0.f;
#pragma unroll
  for (int i = 0; i < 16; ++i) a += bf2f(xnT[(size_t)f * NB + t + 256 * i]);
  a = wave_reduce_sum(a);
  if (lane == 0) red[wid] = a;
  __syncthreads();
  if (t == 0) s[f] = red[0] + red[1] + red[2] + red[3];
}

// ---------------- Gram split-K reduce: [16][256][512] -> G | M2T ------------
// cols 0-255 -> t23B rows 0-255 (G, symmetric); cols 256-511 -> M2T
__global__ __launch_bounds__(256) void reduce16g_kernel(
    const float* __restrict__ in, ushort* __restrict__ t23B,
    ushort* __restrict__ M2T) {
  const int idx = blockIdx.x * 256 + threadIdx.x;   // over 256*512
  const int i = idx >> 9, j = idx & 511;
  float a = 0.f;
#pragma unroll
  for (int z = 0; z < 16; ++z) a += in[(size_t)z * (256 * 512) + idx];
  if (j < 256) t23B[i * 256 + j] = f2bf(a);
  else M2T[i * 256 + (j - 256)] = f2bf(a);
}

// ---------------- row softmax: S bf16 -> P bf16 -----------------------------
__global__ __launch_bounds__(256) void softmax_kernel(
    const ushort* __restrict__ S, ushort* __restrict__ P) {
  __shared__ float red[4];
  const int r = blockIdx.x, t = threadIdx.x, wid = t >> 6, lane = t & 63;
  const uint4* Sr = (const uint4*)(S + (size_t)r * NB);
  float v[16];
  float lmax = -1e30f;
#pragma unroll
  for (int i = 0; i < 2; ++i) {
    const uint4 c = Sr[t + 256 * i];
    const uint32_t w4[4] = {c.x, c.y, c.z, c.w};
#pragma unroll
    for (int j = 0; j < 4; ++j) {
      v[i * 8 + j * 2]     = bf2f((ushort)(w4[j] & 0xffffu));
      v[i * 8 + j * 2 + 1] = bf2f((ushort)(w4[j] >> 16));
    }
  }
#pragma unroll
  for (int u = 0; u < 16; ++u) lmax = fmaxf(lmax, v[u]);
  lmax = wave_reduce_max(lmax);
  if (lane == 0) red[wid] = lmax;
  __syncthreads();
  const float gmax = fmaxf(fmaxf(red[0], red[1]), fmaxf(red[2], red[3]));
  __syncthreads();
  float lsum = 0.f;
#pragma unroll
  for (int u = 0; u < 16; ++u) { v[u] = __expf(v[u] - gmax); lsum += v[u]; }
  lsum = wave_reduce_sum(lsum);
  if (lane == 0) red[wid] = lsum;
  __syncthreads();
  const float pinv = 1.f / (red[0] + red[1] + red[2] + red[3]);
  uint4* Pr = (uint4*)(P + (size_t)r * NB);
#pragma unroll
  for (int i = 0; i < 2; ++i) {
    uint4 o;
    o.x = (uint32_t)f2bf(v[i*8+0] * pinv) | ((uint32_t)f2bf(v[i*8+1] * pinv) << 16);
    o.y = (uint32_t)f2bf(v[i*8+2] * pinv) | ((uint32_t)f2bf(v[i*8+3] * pinv) << 16);
    o.z = (uint32_t)f2bf(v[i*8+4] * pinv) | ((uint32_t)f2bf(v[i*8+5] * pinv) << 16);
    o.w = (uint32_t)f2bf(v[i*8+6] * pinv) | ((uint32_t)f2bf(v[i*8+7] * pinv) << 16);
    Pr[t + 256 * i] = o;
  }
}

// ---------------- mega combine: both outputs --------------------------------
// Per row i: ax=sum_z px, ah=sum_z ph; t2v=t23[i][f], t3v=t23[i][256+f];
// rs = sum_f xn*sv, rq = sum_f xn*t2v -> sd; statsterm = rank-3 w_vB update.
// out_x = mBx*ax + mAx*t2v + x ;  out_h = elu(mBh*ah + mAh*t3v + statsterm) + h
__global__ __launch_bounds__(256) void megacombine_kernel(
    const ushort* __restrict__ px, const ushort* __restrict__ ph,
    const float* __restrict__ t23, const ushort* __restrict__ xnb,
    const float* __restrict__ sv, const float* __restrict__ diag,
    const float* __restrict__ x, const float* __restrict__ h,
    const float* __restrict__ wvbT3, const float* __restrict__ mix,
    float* __restrict__ out_x, float* __restrict__ out_h) {
  __shared__ float rA[4], rB[4];
  const size_t NF = (size_t)NB * FD;
  const int i = blockIdx.x, f = threadIdx.x, wid = f >> 6, lane = f & 63;
  const float e0x = __expf(mix[0]), e1x = __expf(mix[2]);
  const float mAx = e0x / (e0x + e1x), mBx = e1x / (e0x + e1x);
  const float e0h = __expf(mix[1]), e1h = __expf(mix[3]);
  const float mAh = e0h / (e0h + e1h), mBh = e1h / (e0h + e1h);

  const size_t rowoff = (size_t)i * FD + f;
  float ax = 0.f, ah = 0.f;
#pragma unroll
  for (int z = 0; z < 8; ++z) {
    ax += bf2f(px[(size_t)z * NF + rowoff]);
    ah += bf2f(ph[(size_t)z * NF + rowoff]);
  }
  const float t2v = t23[(size_t)i * 512 + f];
  const float t3v = t23[(size_t)i * 512 + 256 + f];
  const float xv = bf2f(xnb[rowoff]);

  float rs = wave_reduce_sum(xv * sv[f]);
  float rq = wave_reduce_sum(xv * t2v);
  if (lane == 0) { rA[wid] = rs; rB[wid] = rq; }
  __syncthreads();
  rs = rA[0] + rA[1] + rA[2] + rA[3];
  rq = rB[0] + rB[1] + rB[2] + rB[3];
  const float mean = rs * (1.0f / NB);
  const float var = (rq - (float)NB * mean * mean) * (1.0f / (NB - 1));
  const float sd = sqrtf(fmaxf(var, 0.f));
  const float dg = diag[i];
  const float statsterm = dg * wvbT3[f] + rs * wvbT3[256 + f] + sd * wvbT3[512 + f];

  out_x[rowoff] = mBx * ax + mAx * t2v + x[rowoff];
  const float pre = mBh * ah + mAh * t3v + statsterm;
  out_h[rowoff] = ((pre > 0.f) ? pre : expm1f(pre)) + h[rowoff];
}

// ---------------- NT bf16 MFMA GEMM, 2-phase double-buffered ----------------
// C[i,j] = sum_k A[i,k]*B[j,k]
// EPI: 0 fp32*alpha | 1 bf16*alpha | 5 splitK fp32 partial | 6 splitK bf16
template <int BM, int BN, int EPI>
__global__ __launch_bounds__(256) void gemm_nt(
    const ushort* __restrict__ A, int lda,
    const ushort* __restrict__ B, int ldb,
    void* __restrict__ Cp, int ldc, int K, float alpha,
    size_t pstride) {
  constexpr int WAVES_N = (BM <= 32) ? 4 : 2;
  constexpr int WAVES_M = 4 / WAVES_N;
  constexpr int WM = BM / WAVES_M, WN = BN / WAVES_N;
  constexpr int MR = WM / 16, NR = WN / 16;
  __shared__ __align__(16) ushort At[2][BM][32];
  __shared__ __align__(16) ushort Bt[2][BN][32];
  const int tid = threadIdx.x;
  const int wave = tid >> 6, lane = tid & 63;
  const int wr = wave / WAVES_N, wc = wave % WAVES_N;
  const int bi = blockIdx.y * BM, bj = blockIdx.x * BN;
  const int fr = lane & 15, fq = lane >> 4;
  const int sub = lane >> 2, q = lane & 3;

  f32x4 acc[MR][NR];
#pragma unroll
  for (int m = 0; m < MR; ++m)
#pragma unroll
    for (int n = 0; n < NR; ++n) acc[m][n] = (f32x4){0.f, 0.f, 0.f, 0.f};

  const int kbase = (EPI >= 5) ? (int)blockIdx.z * K : 0;
  const int kend = kbase + K;

  auto stage = [&](int bufi, int k0) {
    for (int c = wave; c < BM / 16; c += 4) {
      const int row = c * 16 + sub;
      const int qs = q ^ (row & 3);
      gld16(A + (size_t)(bi + row) * lda + k0 + qs * 8, &At[bufi][c * 16][0]);
    }
    for (int c = wave; c < BN / 16; c += 4) {
      const int row = c * 16 + sub;
      const int qs = q ^ (row & 3);
      gld16(B + (size_t)(bj + row) * ldb + k0 + qs * 8, &Bt[bufi][c * 16][0]);
    }
  };

  stage(0, kbase);
  __syncthreads();

  int cur = 0;
  for (int k0 = kbase; k0 < kend; k0 += 32) {
    if (k0 + 32 < kend) stage(cur ^ 1, k0 + 32);
    bf16x8 a[MR], b[NR];
#pragma unroll
    for (int m = 0; m < MR; ++m) {
      const int row = wr * WM + m * 16 + fr;
      a[m] = *(const bf16x8*)((const char*)&At[cur][row][0] + ((fq ^ (row & 3)) * 16));
    }
#pragma unroll
    for (int n = 0; n < NR; ++n) {
      const int row = wc * WN + n * 16 + fr;
      b[n] = *(const bf16x8*)((const char*)&Bt[cur][row][0] + ((fq ^ (row & 3)) * 16));
    }
#pragma unroll
    for (int m = 0; m < MR; ++m)
#pragma unroll
      for (int n = 0; n < NR; ++n)
        acc[m][n] = __builtin_amdgcn_mfma_f32_16x16x32_bf16(a[m], b[n], acc[m][n], 0, 0, 0);
    __syncthreads();
    cur ^= 1;
  }

#pragma unroll
  for (int m = 0; m < MR; ++m)
#pragma unroll
    for (int n = 0; n < NR; ++n)
#pragma unroll
      for (int r = 0; r < 4; ++r) {
        const int row = bi + wr * WM + m * 16 + fq * 4 + r;
        const int col = bj + wc * WN + n * 16 + fr;
        const size_t ci = (size_t)row * ldc + col;
        const float v = acc[m][n][r];
        if (EPI == 0) ((float*)Cp)[ci] = v * alpha;
        else if (EPI == 1) ((ushort*)Cp)[ci] = f2bf(v * alpha);
        else if (EPI == 5) ((float*)Cp)[(size_t)blockIdx.z * pstride + ci] = v;
        else if (EPI == 6) ((ushort*)Cp)[(size_t)blockIdx.z * pstride + ci] = f2bf(v);
      }
}

// ---------------------------------------------------------------------------
extern "C" void kernel_launch(void* const* d_in, const int* in_sizes, int n_in,
                              void* d_out, int out_size, void* d_ws, size_t ws_size,
                              hipStream_t stream) {
  const float* h      = (const float*)d_in[0];
  const float* x      = (const float*)d_in[1];
  const float* w_k    = (const float*)d_in[2];
  const float* w_q    = (const float*)d_in[3];
  const float* w_v    = (const float*)d_in[4];
  const float* mixing = (const float*)d_in[5];
  const float* gamma  = (const float*)d_in[6];
  const float* beta   = (const float*)d_in[7];

  float* out_h = (float*)d_out;
  float* out_x = out_h + (size_t)NB * FD;

  char* w = (char*)d_ws;
  ushort* S     = (ushort*)(w + 0);           // 32MB bf16 scores
  ushort* P     = (ushort*)(w + 33554432);    // 32MB
  ushort* PT    = (ushort*)(w + 67108864);    // 32MB
  ushort* hnb   = (ushort*)(w + 100663296);   // 2MB
  ushort* xnb   = (ushort*)(w + 102760448);   // 2MB
  ushort* xnbT  = (ushort*)(w + 104857600);   // 2MB  [256][NB]  (stack base)
  ushort* hnbT  = (ushort*)(w + 106954752);   // 2MB  [256][NB]  (stack rows 256-511)
  ushort* kq    = (ushort*)(w + 109051904);   // 4MB  [NB][512]
  ushort* hvT   = (ushort*)(w + 113246208);   // 2MB  [256][NB]
  float*  t23   = (float*)(w + 115343360);    // 8MB  [NB][512]
  ushort* t23B  = (ushort*)(w + 123731968);   // 256KB [512][256]  (G | Bv)
  ushort* M2T   = (ushort*)(w + 123994112);   // 128KB [256][256]
  ushort* wkqb  = (ushort*)(w + 124125184);   // 256KB [512][256]
  ushort* wvAb  = (ushort*)(w + 124387328);   // 128KB [256][256]
  float*  wvbT3 = (float*)(w + 124518400);    // 3KB  [3][256]
  float*  diag  = (float*)(w + 124521472);    // 16KB
  float*  sv    = (float*)(w + 124537856);    // 1KB
  // aliases (disjoint lifetimes):
  float*  Gramp = (float*)(w + 67108864);     // 8MB in PT region (dead before PT)
  ushort* px    = (ushort*)(w + 0);           // 16MB in S region (S dead after softmax)
  ushort* ph    = (ushort*)(w + 16777216);    // 16MB

  rownorm_kernel<<<NB, 256, 0, stream>>>(h, x, gamma, beta, hnb, xnb, diag);
  wcast_kernel<<<FD, 256, 0, stream>>>(w_k, w_q, w_v, wkqb, wvAb, wvbT3);
  transpose_kernel<<<dim3(FD / 64, NB / 64), 256, 0, stream>>>(xnb, xnbT, NB, FD);
  transpose_kernel<<<dim3(FD / 64, NB / 64), 256, 0, stream>>>(hnb, hnbT, NB, FD);
  colsum_kernel<<<FD, 256, 0, stream>>>(xnbT, sv);

  // kq = hn @ [w_k; w_q]^T   -> [NB, 512] bf16
  gemm_nt<64, 64, 1><<<dim3(512 / 64, NB / 64), 256, 0, stream>>>(
      hnb, FD, wkqb, FD, kq, 512, FD, 1.f, 0);

  // Gram stacked: C[256, 512] = xnT rows x [xnT; hnT] rows, split-K 16
  //   cols 0-255 -> G, cols 256-511 -> M2T = xn^T @ hn
  gemm_nt<64, 64, 5><<<dim3(512 / 64, 256 / 64, 16), 256, 0, stream>>>(
      xnbT, NB, xnbT, NB, Gramp, 512, NB / 16, 1.f, (size_t)256 * 512);
  reduce16g_kernel<<<256 * 512 / 256, 256, 0, stream>>>(Gramp, t23B, M2T);

  // Bv = w_vA @ M2  (via M2T):  Bv[j,k] = sum_m wvA[j,m] * M2T[k,m]
  gemm_nt<64, 64, 1><<<dim3(4, 4), 256, 0, stream>>>(
      wvAb, FD, M2T, FD, t23B + 256 * 256, FD, FD, 1.f, 0);

  // hvT = w_vA @ hn^T  -> [256, NB] bf16
  gemm_nt<64, 64, 1><<<dim3(NB / 64, FD / 64), 256, 0, stream>>>(
      wvAb, FD, hnb, FD, hvT, NB, FD, 1.f, 0);

  // t23 = xn @ [G; Bv]^T -> [NB, 512] fp32 (t2 | t3v)
  gemm_nt<64, 64, 0><<<dim3(512 / 64, NB / 64), 256, 0, stream>>>(
      xnb, FD, t23B, FD, t23, 512, FD, 1.f, 0);

  // S = bf16((k @ q^T) / 16)
  gemm_nt<128, 128, 1><<<dim3(NB / 128, NB / 128), 256, 0, stream>>>(
      kq, 512, kq + 256, 512, S, NB, FD, 0.0625f, 0);
  softmax_kernel<<<NB, 256, 0, stream>>>(S, P);
  transpose_kernel<<<dim3(NB / 64, NB / 64), 256, 0, stream>>>(P, PT, NB, NB);

  // aggregation partials: 128x128 tiles, split-K 8
  gemm_nt<128, 128, 6><<<dim3(FD / 128, NB / 128, 8), 256, 0, stream>>>(
      P, NB, xnbT, NB, px, FD, NB / 8, 1.f, (size_t)NB * FD);
  gemm_nt<128, 128, 6><<<dim3(FD / 128, NB / 128, 8), 256, 0, stream>>>(
      PT, NB, hvT, NB, ph, FD, NB / 8, 1.f, (size_t)NB * FD);

  // mega combine -> out_x, out_h
  megacombine_kernel<<<NB, 256, 0, stream>>>(
      px, ph, t23, xnb, sv, diag, x, h, wvbT3, mixing, out_x, out_h);
}

// Round 8
// 140.797 us; speedup vs baseline: 1.3545x; 1.0474x over previous
//
#include <hip/hip_runtime.h>
#include <cstdint>
#include <cstddef>

#define NB 4096
#define FD 256

typedef __attribute__((ext_vector_type(4))) float f32x4;
typedef __attribute__((ext_vector_type(8))) short bf16x8;

__device__ __forceinline__ ushort f2bf(float f) {
  union { float f; uint32_t u; } v; v.f = f;
  uint32_t r = v.u + 0x7fffu + ((v.u >> 16) & 1u);
  return (ushort)(r >> 16);
}
__device__ __forceinline__ float bf2f(ushort b) {
  union { uint32_t u; float f; } v; v.u = ((uint32_t)b) << 16;
  return v.f;
}

__device__ __forceinline__ void gld16(const void* g, void* l) {
  __builtin_amdgcn_global_load_lds(
      (const __attribute__((address_space(1))) char*)g,
      (__attribute__((address_space(3))) char*)l, 16, 0, 0);
}

__device__ __forceinline__ float wave_reduce_sum(float v) {
#pragma unroll
  for (int off = 32; off >= 1; off >>= 1) v += __shfl_xor(v, off);
  return v;
}
__device__ __forceinline__ float wave_reduce_max(float v) {
#pragma unroll
  for (int off = 32; off >= 1; off >>= 1) v = fmaxf(v, __shfl_xor(v, off));
  return v;
}

// ---------------- rownorm ---------------------------------------------------
__global__ __launch_bounds__(256) void rownorm_kernel(
    const float* __restrict__ h, const float* __restrict__ x,
    const float* __restrict__ gamma, const float* __restrict__ beta,
    ushort* __restrict__ hnb, ushort* __restrict__ xnb, float* __restrict__ diag) {
  __shared__ float rA[4], rB[4], rC[4], rD[4];
  const int r = blockIdx.x, t = threadIdx.x, wid = t >> 6, lane = t & 63;
  const size_t base = (size_t)r * FD + t;
  const float hv = h[base], xv = x[base];
  float s1 = wave_reduce_sum(hv);
  float s2 = wave_reduce_sum(hv * hv);
  float a1 = wave_reduce_sum(fabsf(xv));
  float q1 = wave_reduce_sum(xv * xv);
  if (lane == 0) { rA[wid] = s1; rB[wid] = s2; rC[wid] = a1; rD[wid] = q1; }
  __syncthreads();
  const float S1 = rA[0] + rA[1] + rA[2] + rA[3];
  const float S2 = rB[0] + rB[1] + rB[2] + rB[3];
  const float L1 = rC[0] + rC[1] + rC[2] + rC[3];
  const float Q1 = rD[0] + rD[1] + rD[2] + rD[3];
  const float mu = S1 * (1.0f / FD);
  const float var = S2 * (1.0f / FD) - mu * mu;
  const float rstd = rsqrtf(var + 1e-5f);
  const float d = fmaxf(L1, 1e-12f), dinv = 1.0f / d;
  hnb[base] = f2bf((hv - mu) * rstd * gamma[t] + beta[t]);
  xnb[base] = f2bf(xv * dinv);
  if (t == 0) diag[r] = Q1 * dinv * dinv;
}

// ---------------- weight casts ----------------------------------------------
__global__ __launch_bounds__(256) void wcast_kernel(
    const float* __restrict__ w_k, const float* __restrict__ w_q,
    const float* __restrict__ w_v,
    ushort* __restrict__ wkqb, ushort* __restrict__ wvAb,
    float* __restrict__ wvbT3) {
  const int r = blockIdx.x, t = threadIdx.x;
  wkqb[r * 256 + t] = f2bf(w_k[r * 256 + t]);
  wkqb[(256 + r) * 256 + t] = f2bf(w_q[r * 256 + t]);
  wvAb[r * 256 + t] = f2bf(w_v[(size_t)r * 259 + t]);
  if (t < 3) wvbT3[t * 256 + r] = w_v[(size_t)r * 259 + 256 + t];
}

// ---------------- bf16 transpose (64x64 tiles); z selects src/dst pair ------
__global__ __launch_bounds__(256) void transpose2_kernel(
    const ushort* __restrict__ inA, ushort* __restrict__ outA,
    const ushort* __restrict__ inB, ushort* __restrict__ outB, int R, int C) {
  __shared__ ushort tile[64][65];
  const ushort* in = blockIdx.z ? inB : inA;
  ushort* out = blockIdx.z ? outB : outA;
  const int bc = blockIdx.x * 64, br = blockIdx.y * 64;
  const int t = threadIdx.x;
#pragma unroll
  for (int i = 0; i < 16; ++i) {
    const int idx = t + 256 * i;
    const int rr = idx >> 6, cc = idx & 63;
    tile[rr][cc] = in[(size_t)(br + rr) * C + bc + cc];
  }
  __syncthreads();
#pragma unroll
  for (int i = 0; i < 16; ++i) {
    const int idx = t + 256 * i;
    const int rr = idx >> 6, cc = idx & 63;
    out[(size_t)(bc + rr) * R + br + cc] = tile[cc][rr];
  }
}

__global__ __launch_bounds__(256) void transpose_kernel(
    const ushort* __restrict__ in, ushort* __restrict__ out, int R, int C) {
  __shared__ ushort tile[64][65];
  const int bc = blockIdx.x * 64, br = blockIdx.y * 64;
  const int t = threadIdx.x;
#pragma unroll
  for (int i = 0; i < 16; ++i) {
    const int idx = t + 256 * i;
    const int rr = idx >> 6, cc = idx & 63;
    tile[rr][cc] = in[(size_t)(br + rr) * C + bc + cc];
  }
  __syncthreads();
#pragma unroll
  for (int i = 0; i < 16; ++i) {
    const int idx = t + 256 * i;
    const int rr = idx >> 6, cc = idx & 63;
    out[(size_t)(bc + rr) * R + br + cc] = tile[cc][rr];
  }
}

// ---------------- colsum of xn ----------------------------------------------
__global__ __launch_bounds__(256) void colsum_kernel(
    const ushort* __restrict__ xnT, float* __restrict__ s) {
  __shared__ float red[4];
  const int f = blockIdx.x, t = threadIdx.x, wid = t >> 6, lane = t & 63;
  float a = 0.f;
#pragma unroll
  for (int i = 0; i < 16; ++i) a += bf2f(xnT[(size_t)f * NB + t + 256 * i]);
  a = wave_reduce_sum(a);
  if (lane == 0) red[wid] = a;
  __syncthreads();
  if (t == 0) s[f] = red[0] + red[1] + red[2] + red[3];
}

// ---------------- Gram split-K reduce: [16][256][512] -> G | M2T ------------
__global__ __launch_bounds__(256) void reduce16g_kernel(
    const float* __restrict__ in, ushort* __restrict__ t23B,
    ushort* __restrict__ M2T) {
  const int idx = blockIdx.x * 256 + threadIdx.x;   // over 256*512
  const int i = idx >> 9, j = idx & 511;
  float a = 0.f;
#pragma unroll
  for (int z = 0; z < 16; ++z) a += in[(size_t)z * (256 * 512) + idx];
  if (j < 256) t23B[i * 256 + j] = f2bf(a);
  else M2T[i * 256 + (j - 256)] = f2bf(a);
}

// ---------------- row softmax: S bf16 -> P bf16 -----------------------------
__global__ __launch_bounds__(256) void softmax_kernel(
    const ushort* __restrict__ S, ushort* __restrict__ P) {
  __shared__ float red[4];
  const int r = blockIdx.x, t = threadIdx.x, wid = t >> 6, lane = t & 63;
  const uint4* Sr = (const uint4*)(S + (size_t)r * NB);
  float v[16];
  float lmax = -1e30f;
#pragma unroll
  for (int i = 0; i < 2; ++i) {
    const uint4 c = Sr[t + 256 * i];
    const uint32_t w4[4] = {c.x, c.y, c.z, c.w};
#pragma unroll
    for (int j = 0; j < 4; ++j) {
      v[i * 8 + j * 2]     = bf2f((ushort)(w4[j] & 0xffffu));
      v[i * 8 + j * 2 + 1] = bf2f((ushort)(w4[j] >> 16));
    }
  }
#pragma unroll
  for (int u = 0; u < 16; ++u) lmax = fmaxf(lmax, v[u]);
  lmax = wave_reduce_max(lmax);
  if (lane == 0) red[wid] = lmax;
  __syncthreads();
  const float gmax = fmaxf(fmaxf(red[0], red[1]), fmaxf(red[2], red[3]));
  __syncthreads();
  float lsum = 0.f;
#pragma unroll
  for (int u = 0; u < 16; ++u) { v[u] = __expf(v[u] - gmax); lsum += v[u]; }
  lsum = wave_reduce_sum(lsum);
  if (lane == 0) red[wid] = lsum;
  __syncthreads();
  const float pinv = 1.f / (red[0] + red[1] + red[2] + red[3]);
  uint4* Pr = (uint4*)(P + (size_t)r * NB);
#pragma unroll
  for (int i = 0; i < 2; ++i) {
    uint4 o;
    o.x = (uint32_t)f2bf(v[i*8+0] * pinv) | ((uint32_t)f2bf(v[i*8+1] * pinv) << 16);
    o.y = (uint32_t)f2bf(v[i*8+2] * pinv) | ((uint32_t)f2bf(v[i*8+3] * pinv) << 16);
    o.z = (uint32_t)f2bf(v[i*8+4] * pinv) | ((uint32_t)f2bf(v[i*8+5] * pinv) << 16);
    o.w = (uint32_t)f2bf(v[i*8+6] * pinv) | ((uint32_t)f2bf(v[i*8+7] * pinv) << 16);
    Pr[t + 256 * i] = o;
  }
}

// ---------------- mega combine: both outputs --------------------------------
__global__ __launch_bounds__(256) void megacombine_kernel(
    const ushort* __restrict__ px, const ushort* __restrict__ ph,
    const float* __restrict__ t23, const ushort* __restrict__ xnb,
    const float* __restrict__ sv, const float* __restrict__ diag,
    const float* __restrict__ x, const float* __restrict__ h,
    const float* __restrict__ wvbT3, const float* __restrict__ mix,
    float* __restrict__ out_x, float* __restrict__ out_h) {
  __shared__ float rA[4], rB[4];
  const size_t NF = (size_t)NB * FD;
  const int i = blockIdx.x, f = threadIdx.x, wid = f >> 6, lane = f & 63;
  const float e0x = __expf(mix[0]), e1x = __expf(mix[2]);
  const float mAx = e0x / (e0x + e1x), mBx = e1x / (e0x + e1x);
  const float e0h = __expf(mix[1]), e1h = __expf(mix[3]);
  const float mAh = e0h / (e0h + e1h), mBh = e1h / (e0h + e1h);

  const size_t rowoff = (size_t)i * FD + f;
  float ax = 0.f, ah = 0.f;
#pragma unroll
  for (int z = 0; z < 8; ++z) {
    ax += bf2f(px[(size_t)z * NF + rowoff]);
    ah += bf2f(ph[(size_t)z * NF + rowoff]);
  }
  const float t2v = t23[(size_t)i * 512 + f];
  const float t3v = t23[(size_t)i * 512 + 256 + f];
  const float xv = bf2f(xnb[rowoff]);

  float rs = wave_reduce_sum(xv * sv[f]);
  float rq = wave_reduce_sum(xv * t2v);
  if (lane == 0) { rA[wid] = rs; rB[wid] = rq; }
  __syncthreads();
  rs = rA[0] + rA[1] + rA[2] + rA[3];
  rq = rB[0] + rB[1] + rB[2] + rB[3];
  const float mean = rs * (1.0f / NB);
  const float var = (rq - (float)NB * mean * mean) * (1.0f / (NB - 1));
  const float sd = sqrtf(fmaxf(var, 0.f));
  const float dg = diag[i];
  const float statsterm = dg * wvbT3[f] + rs * wvbT3[256 + f] + sd * wvbT3[512 + f];

  out_x[rowoff] = mBx * ax + mAx * t2v + x[rowoff];
  const float pre = mBh * ah + mAh * t3v + statsterm;
  out_h[rowoff] = ((pre > 0.f) ? pre : expm1f(pre)) + h[rowoff];
}

// ---------------- NT bf16 MFMA GEMM, 2-phase dbuf + XCD swizzle -------------
// C[i,j] = sum_k A[i,k]*B[j,k]
// EPI: 0 fp32*alpha | 1 bf16*alpha | 5 splitK fp32 partial | 6 splitK bf16
template <int BM, int BN, int EPI>
__global__ __launch_bounds__(256) void gemm_nt(
    const ushort* __restrict__ A, int lda,
    const ushort* __restrict__ B, int ldb,
    void* __restrict__ Cp, int ldc, int K, float alpha,
    size_t pstride) {
  constexpr int WAVES_N = (BM <= 32) ? 4 : 2;
  constexpr int WAVES_M = 4 / WAVES_N;
  constexpr int WM = BM / WAVES_M, WN = BN / WAVES_N;
  constexpr int MR = WM / 16, NR = WN / 16;
  __shared__ __align__(16) ushort At[2][BM][32];
  __shared__ __align__(16) ushort Bt[2][BN][32];
  const int tid = threadIdx.x;
  const int wave = tid >> 6, lane = tid & 63;
  const int wr = wave / WAVES_N, wc = wave % WAVES_N;

  // T1: bijective XCD-chunk swizzle of the flattened block id (nwg % 8 == 0)
  const int gx = gridDim.x, gy = gridDim.y;
  const int nwg = gx * gy * gridDim.z;
  int flat = blockIdx.x + gx * (blockIdx.y + gy * blockIdx.z);
  if ((nwg & 7) == 0) flat = (flat & 7) * (nwg >> 3) + (flat >> 3);
  const int bx = flat % gx, by = (flat / gx) % gy, bz = flat / (gx * gy);

  const int bi = by * BM, bj = bx * BN;
  const int fr = lane & 15, fq = lane >> 4;
  const int sub = lane >> 2, q = lane & 3;

  f32x4 acc[MR][NR];
#pragma unroll
  for (int m = 0; m < MR; ++m)
#pragma unroll
    for (int n = 0; n < NR; ++n) acc[m][n] = (f32x4){0.f, 0.f, 0.f, 0.f};

  const int kbase = (EPI >= 5) ? bz * K : 0;
  const int kend = kbase + K;

  auto stage = [&](int bufi, int k0) {
    for (int c = wave; c < BM / 16; c += 4) {
      const int row = c * 16 + sub;
      const int qs = q ^ (row & 3);
      gld16(A + (size_t)(bi + row) * lda + k0 + qs * 8, &At[bufi][c * 16][0]);
    }
    for (int c = wave; c < BN / 16; c += 4) {
      const int row = c * 16 + sub;
      const int qs = q ^ (row & 3);
      gld16(B + (size_t)(bj + row) * ldb + k0 + qs * 8, &Bt[bufi][c * 16][0]);
    }
  };

  stage(0, kbase);
  __syncthreads();

  int cur = 0;
  for (int k0 = kbase; k0 < kend; k0 += 32) {
    if (k0 + 32 < kend) stage(cur ^ 1, k0 + 32);
    bf16x8 a[MR], b[NR];
#pragma unroll
    for (int m = 0; m < MR; ++m) {
      const int row = wr * WM + m * 16 + fr;
      a[m] = *(const bf16x8*)((const char*)&At[cur][row][0] + ((fq ^ (row & 3)) * 16));
    }
#pragma unroll
    for (int n = 0; n < NR; ++n) {
      const int row = wc * WN + n * 16 + fr;
      b[n] = *(const bf16x8*)((const char*)&Bt[cur][row][0] + ((fq ^ (row & 3)) * 16));
    }
#pragma unroll
    for (int m = 0; m < MR; ++m)
#pragma unroll
      for (int n = 0; n < NR; ++n)
        acc[m][n] = __builtin_amdgcn_mfma_f32_16x16x32_bf16(a[m], b[n], acc[m][n], 0, 0, 0);
    __syncthreads();
    cur ^= 1;
  }

#pragma unroll
  for (int m = 0; m < MR; ++m)
#pragma unroll
    for (int n = 0; n < NR; ++n)
#pragma unroll
      for (int r = 0; r < 4; ++r) {
        const int row = bi + wr * WM + m * 16 + fq * 4 + r;
        const int col = bj + wc * WN + n * 16 + fr;
        const size_t ci = (size_t)row * ldc + col;
        const float v = acc[m][n][r];
        if (EPI == 0) ((float*)Cp)[ci] = v * alpha;
        else if (EPI == 1) ((ushort*)Cp)[ci] = f2bf(v * alpha);
        else if (EPI == 5) ((float*)Cp)[(size_t)bz * pstride + ci] = v;
        else if (EPI == 6) ((ushort*)Cp)[(size_t)bz * pstride + ci] = f2bf(v);
      }
}

// ---------------------------------------------------------------------------
extern "C" void kernel_launch(void* const* d_in, const int* in_sizes, int n_in,
                              void* d_out, int out_size, void* d_ws, size_t ws_size,
                              hipStream_t stream) {
  const float* h      = (const float*)d_in[0];
  const float* x      = (const float*)d_in[1];
  const float* w_k    = (const float*)d_in[2];
  const float* w_q    = (const float*)d_in[3];
  const float* w_v    = (const float*)d_in[4];
  const float* mixing = (const float*)d_in[5];
  const float* gamma  = (const float*)d_in[6];
  const float* beta   = (const float*)d_in[7];

  float* out_h = (float*)d_out;
  float* out_x = out_h + (size_t)NB * FD;

  char* w = (char*)d_ws;
  ushort* S     = (ushort*)(w + 0);           // 32MB bf16 scores
  ushort* P     = (ushort*)(w + 33554432);    // 32MB
  ushort* PT    = (ushort*)(w + 67108864);    // 32MB
  ushort* hnb   = (ushort*)(w + 100663296);   // 2MB
  ushort* xnb   = (ushort*)(w + 102760448);   // 2MB
  ushort* xnbT  = (ushort*)(w + 104857600);   // 2MB  [256][NB]
  ushort* hnbT  = (ushort*)(w + 106954752);   // 2MB  [256][NB]
  ushort* kq    = (ushort*)(w + 109051904);   // 4MB  [NB][512]
  ushort* hvT   = (ushort*)(w + 113246208);   // 2MB  [256][NB]
  float*  t23   = (float*)(w + 115343360);    // 8MB  [NB][512]
  ushort* t23B  = (ushort*)(w + 123731968);   // 256KB [512][256]  (G | Bv)
  ushort* M2T   = (ushort*)(w + 123994112);   // 128KB
  ushort* wkqb  = (ushort*)(w + 124125184);   // 256KB [512][256]
  ushort* wvAb  = (ushort*)(w + 124387328);   // 128KB
  float*  wvbT3 = (float*)(w + 124518400);    // 3KB
  float*  diag  = (float*)(w + 124521472);    // 16KB
  float*  sv    = (float*)(w + 124537856);    // 1KB
  // aliases (disjoint lifetimes):
  float*  Gramp = (float*)(w + 67108864);     // 8MB in PT region (dead before PT)
  ushort* px    = (ushort*)(w + 0);           // 16MB in S region (S dead after softmax)
  ushort* ph    = (ushort*)(w + 16777216);    // 16MB

  rownorm_kernel<<<NB, 256, 0, stream>>>(h, x, gamma, beta, hnb, xnb, diag);
  wcast_kernel<<<FD, 256, 0, stream>>>(w_k, w_q, w_v, wkqb, wvAb, wvbT3);
  transpose2_kernel<<<dim3(FD / 64, NB / 64, 2), 256, 0, stream>>>(
      xnb, xnbT, hnb, hnbT, NB, FD);
  colsum_kernel<<<FD, 256, 0, stream>>>(xnbT, sv);

  // kq = hn @ [w_k; w_q]^T   -> [NB, 512] bf16
  gemm_nt<64, 64, 1><<<dim3(512 / 64, NB / 64), 256, 0, stream>>>(
      hnb, FD, wkqb, FD, kq, 512, FD, 1.f, 0);

  // Gram stacked: C[256, 512], split-K 16 (cols 0-255 -> G, 256-511 -> M2T)
  gemm_nt<64, 64, 5><<<dim3(512 / 64, 256 / 64, 16), 256, 0, stream>>>(
      xnbT, NB, xnbT, NB, Gramp, 512, NB / 16, 1.f, (size_t)256 * 512);
  reduce16g_kernel<<<256 * 512 / 256, 256, 0, stream>>>(Gramp, t23B, M2T);

  // Bv = w_vA @ M2 (via M2T)
  gemm_nt<64, 64, 1><<<dim3(4, 4), 256, 0, stream>>>(
      wvAb, FD, M2T, FD, t23B + 256 * 256, FD, FD, 1.f, 0);

  // hvT = w_vA @ hn^T  -> [256, NB] bf16
  gemm_nt<64, 64, 1><<<dim3(NB / 64, FD / 64), 256, 0, stream>>>(
      wvAb, FD, hnb, FD, hvT, NB, FD, 1.f, 0);

  // t23 = xn @ [G; Bv]^T -> [NB, 512] fp32
  gemm_nt<64, 64, 0><<<dim3(512 / 64, NB / 64), 256, 0, stream>>>(
      xnb, FD, t23B, FD, t23, 512, FD, 1.f, 0);

  // S = bf16((k @ q^T) / 16)
  gemm_nt<128, 128, 1><<<dim3(NB / 128, NB / 128), 256, 0, stream>>>(
      kq, 512, kq + 256, 512, S, NB, FD, 0.0625f, 0);
  softmax_kernel<<<NB, 256, 0, stream>>>(S, P);
  transpose_kernel<<<dim3(NB / 64, NB / 64), 256, 0, stream>>>(P, PT, NB, NB);

  // aggregation partials: 128x128 tiles, split-K 8
  gemm_nt<128, 128, 6><<<dim3(FD / 128, NB / 128, 8), 256, 0, stream>>>(
      P, NB, xnbT, NB, px, FD, NB / 8, 1.f, (size_t)NB * FD);
  gemm_nt<128, 128, 6><<<dim3(FD / 128, NB / 128, 8), 256, 0, stream>>>(
      PT, NB, hvT, NB, ph, FD, NB / 8, 1.f, (size_t)NB * FD);

  // mega combine -> out_x, out_h
  megacombine_kernel<<<NB, 256, 0, stream>>>(
      px, ph, t23, xnb, sv, diag, x, h, wvbT3, mixing, out_x, out_h);
}